// Round 1
// baseline (616.248 us; speedup 1.0000x reference)
//
#include <hip/hip_runtime.h>

#define OUT_HH 7
#define OUT_WW 7
#define MAXG 4

// One block handles one ROI x one chunk of channels.
// Geometry (bilinear indices/weights per output pixel x grid slot) is shared
// across all channels -> precompute into LDS once per block.
__global__ __launch_bounds__(256, 4) void roi_align_kernel(
    const float* __restrict__ feat,
    const float* __restrict__ rois,
    float* __restrict__ out,
    int B, int C, int H, int W, int N, int c_per_blk)
{
    const int n    = blockIdx.x;
    const int cblk = blockIdx.y;

    __shared__ float s_wy0[OUT_HH * MAXG], s_wy1[OUT_HH * MAXG];
    __shared__ float s_wx0[OUT_WW * MAXG], s_wx1[OUT_WW * MAXG];
    __shared__ int   s_ylo[OUT_HH * MAXG], s_yhi[OUT_HH * MAXG];
    __shared__ int   s_xlo[OUT_WW * MAXG], s_xhi[OUT_WW * MAXG];

    const float* roi = rois + (size_t)n * 5;
    const int   b  = (int)roi[0];
    const float x1 = roi[1], y1 = roi[2], x2 = roi[3], y2 = roi[4];
    const float roi_w = fmaxf(x2 - x1, 1.0f);
    const float roi_h = fmaxf(y2 - y1, 1.0f);
    const float bin_h = roi_h / 7.0f;   // exact fp32 division, like the ref
    const float bin_w = roi_w / 7.0f;
    int gh = (int)ceilf(roi_h / 7.0f); gh = min(max(gh, 1), MAXG);
    int gw = (int)ceilf(roi_w / 7.0f); gw = min(max(gw, 1), MAXG);
    const float count = (float)(gh * gw);

    const int t = threadIdx.x;
    if (t < OUT_HH * MAXG) {
        // y-axis table: 7 output rows x 4 grid slots
        const int py = t >> 2, g = t & 3;
        float pos  = y1 + (float)py * bin_h + ((float)g + 0.5f) * bin_h / (float)gh;
        bool valid = (pos >= -1.0f) && (pos <= (float)H);
        float p = fmaxf(pos, 0.0f);
        int lo  = min((int)floorf(p), H - 1);
        int hi  = min(lo + 1, H - 1);
        if (lo >= H - 1) p = (float)(H - 1);
        float frac = p - (float)lo;
        float m = valid ? 1.0f : 0.0f;
        s_ylo[t] = lo; s_yhi[t] = hi;
        s_wy0[t] = (1.0f - frac) * m;
        s_wy1[t] = frac * m;
    } else if (t < 2 * OUT_HH * MAXG) {
        // x-axis table
        const int u = t - OUT_HH * MAXG;
        const int px = u >> 2, g = u & 3;
        float pos  = x1 + (float)px * bin_w + ((float)g + 0.5f) * bin_w / (float)gw;
        bool valid = (pos >= -1.0f) && (pos <= (float)W);
        float p = fmaxf(pos, 0.0f);
        int lo  = min((int)floorf(p), W - 1);
        int hi  = min(lo + 1, W - 1);
        if (lo >= W - 1) p = (float)(W - 1);
        float frac = p - (float)lo;
        float m = valid ? 1.0f : 0.0f;
        s_xlo[u] = lo; s_xhi[u] = hi;
        s_wx0[u] = (1.0f - frac) * m;
        s_wx1[u] = frac * m;
    }
    __syncthreads();

    const int   c0    = cblk * c_per_blk;
    const int   elems = c_per_blk * OUT_HH * OUT_WW;
    const size_t HW   = (size_t)H * W;

    for (int e = t; e < elems; e += 256) {
        const int cl  = e / 49;
        const int pix = e - cl * 49;
        const int py  = pix / 7;
        const int px  = pix - py * 7;
        const int c   = c0 + cl;
        const float* f = feat + (size_t)(b * C + c) * HW;

        float acc = 0.0f;
        for (int gy = 0; gy < gh; ++gy) {
            const int yi  = (py << 2) + gy;
            const int rlo = s_ylo[yi] * W;
            const int rhi = s_yhi[yi] * W;
            const float wy0 = s_wy0[yi], wy1 = s_wy1[yi];
            for (int gx = 0; gx < gw; ++gx) {
                const int xi  = (px << 2) + gx;
                const int xlo = s_xlo[xi], xhi = s_xhi[xi];
                const float wx0 = s_wx0[xi], wx1 = s_wx1[xi];
                const float v00 = f[rlo + xlo];
                const float v01 = f[rlo + xhi];
                const float v10 = f[rhi + xlo];
                const float v11 = f[rhi + xhi];
                acc += wy0 * (wx0 * v00 + wx1 * v01)
                     + wy1 * (wx0 * v10 + wx1 * v11);
            }
        }
        out[((size_t)n * C + c) * (OUT_HH * OUT_WW) + pix] = acc / count;
    }
}

extern "C" void kernel_launch(void* const* d_in, const int* in_sizes, int n_in,
                              void* d_out, int out_size, void* d_ws, size_t ws_size,
                              hipStream_t stream) {
    const float* feat = (const float*)d_in[0];
    const float* rois = (const float*)d_in[1];
    float* out = (float*)d_out;

    const int B = 4, C = 256, H = 200, W = 272;
    const int N = in_sizes[1] / 5;           // 512
    const int c_per_blk = 64;                // 4 channel chunks

    dim3 grid(N, C / c_per_blk);
    roi_align_kernel<<<grid, 256, 0, stream>>>(feat, rois, out,
                                               B, C, H, W, N, c_per_blk);
}

// Round 2
// 405.877 us; speedup vs baseline: 1.5183x; 1.5183x over previous
//
#include <hip/hip_runtime.h>

#define OUT_HH 7
#define OUT_WW 7
#define MAXG 4
#define CPB 8            // channels per block
#define REG_MAX 30       // max region extent per axis (roi<=28 -> span<=30)
#define CH_STRIDE 905    // odd LDS stride per channel (>= 30*30), breaks pow2 banks

// Block = (roi, channel-chunk of 8). Stage the ROI's sampled feature region
// (<=30x30 per channel, contiguous rows in W) into LDS with coalesced loads,
// then all bilinear taps are LDS reads. Geometry tables shared in LDS.
__global__ __launch_bounds__(256) void roi_align_kernel(
    const float* __restrict__ feat,
    const float* __restrict__ rois,
    float* __restrict__ out,
    int B, int C, int H, int W, int N)
{
    const int n    = blockIdx.x;
    const int cblk = blockIdx.y;

    __shared__ float s_feat[CPB * CH_STRIDE];                 // ~28.9 KB
    __shared__ int   s_yrl[OUT_HH * MAXG], s_yrh[OUT_HH * MAXG];  // region row offsets (premul rw)
    __shared__ float s_wy0[OUT_HH * MAXG], s_wy1[OUT_HH * MAXG];
    __shared__ int   s_xcl[OUT_WW * MAXG], s_xch[OUT_WW * MAXG];  // region col offsets
    __shared__ float s_wx0[OUT_WW * MAXG], s_wx1[OUT_WW * MAXG];

    const float* roi = rois + (size_t)n * 5;
    const int   b  = (int)roi[0];
    const float x1 = roi[1], y1 = roi[2], x2 = roi[3], y2 = roi[4];
    const float roi_w = fmaxf(x2 - x1, 1.0f);
    const float roi_h = fmaxf(y2 - y1, 1.0f);
    const float bin_h = roi_h / 7.0f;
    const float bin_w = roi_w / 7.0f;
    int gh = (int)ceilf(roi_h / 7.0f); gh = min(max(gh, 1), MAXG);
    int gw = (int)ceilf(roi_w / 7.0f); gw = min(max(gw, 1), MAXG);
    const float count = (float)(gh * gw);

    // --- region bounds (redundant per-thread scalar math; samples are monotone
    // in (p,g), so min index is at (p=0,g=0) and max at (p=6,g=active_max)).
    auto axis_lo = [](float pos, int size) {
        float p = fmaxf(pos, 0.0f);
        return min((int)floorf(p), size - 1);
    };
    const float ys_min = y1 + 0.5f * bin_h / (float)gh;
    const float ys_max = y1 + 6.0f * bin_h + ((float)(gh - 1) + 0.5f) * bin_h / (float)gh;
    const float xs_min = x1 + 0.5f * bin_w / (float)gw;
    const float xs_max = x1 + 6.0f * bin_w + ((float)(gw - 1) + 0.5f) * bin_w / (float)gw;
    const int y0 = axis_lo(ys_min, H);
    const int yE = min(axis_lo(ys_max, H) + 1, H - 1);   // max yhi
    const int x0 = axis_lo(xs_min, W);
    const int xE = min(axis_lo(xs_max, W) + 1, W - 1);   // max xhi
    int rh = min(yE - y0 + 1, REG_MAX);
    int rw = min(xE - x0 + 1, REG_MAX);
    const int plane = rh * rw;

    const int t = threadIdx.x;

    // --- geometry tables (region-relative; row offsets premultiplied by rw)
    if (t < OUT_HH * MAXG) {
        const int py = t >> 2, g = t & 3;
        float pos  = y1 + (float)py * bin_h + ((float)g + 0.5f) * bin_h / (float)gh;
        bool valid = (pos >= -1.0f) && (pos <= (float)H);
        float p = fmaxf(pos, 0.0f);
        int lo  = min((int)floorf(p), H - 1);
        int hi  = min(lo + 1, H - 1);
        if (lo >= H - 1) p = (float)(H - 1);
        float frac = p - (float)lo;
        float m = valid ? 1.0f : 0.0f;
        s_yrl[t] = (lo - y0) * rw;
        s_yrh[t] = (hi - y0) * rw;
        s_wy0[t] = (1.0f - frac) * m;
        s_wy1[t] = frac * m;
    } else if (t < 2 * OUT_HH * MAXG) {
        const int u = t - OUT_HH * MAXG;
        const int px = u >> 2, g = u & 3;
        float pos  = x1 + (float)px * bin_w + ((float)g + 0.5f) * bin_w / (float)gw;
        bool valid = (pos >= -1.0f) && (pos <= (float)W);
        float p = fmaxf(pos, 0.0f);
        int lo  = min((int)floorf(p), W - 1);
        int hi  = min(lo + 1, W - 1);
        if (lo >= W - 1) p = (float)(W - 1);
        float frac = p - (float)lo;
        float m = valid ? 1.0f : 0.0f;
        s_xcl[u] = lo - x0;
        s_xch[u] = hi - x0;
        s_wx0[u] = (1.0f - frac) * m;
        s_wx1[u] = frac * m;
    }

    // --- stage region for CPB channels (coalesced along W within rows)
    const int    c0 = cblk * CPB;
    const size_t HW = (size_t)H * W;
    const float* fbase = feat + ((size_t)b * C + c0) * HW + (size_t)y0 * W + x0;
    for (int ch = 0; ch < CPB; ++ch) {
        const float* fp = fbase + ch * HW;
        float* sp = s_feat + ch * CH_STRIDE;
        for (int i = t; i < plane; i += 256) {
            const int r = i / rw;
            const int c = i - r * rw;
            sp[i] = fp[r * W + c];
        }
    }
    __syncthreads();

    // --- compute: 8 ch x 49 pix = 392 outputs, all taps from LDS
    const int elems = CPB * 49;
    const size_t out_base = ((size_t)n * C + c0) * 49;
    for (int e = t; e < elems; e += 256) {
        const int cl  = e / 49;
        const int pix = e - cl * 49;
        const int py  = pix / 7;
        const int px  = pix - py * 7;
        const float* sp = s_feat + cl * CH_STRIDE;

        float acc = 0.0f;
        for (int gy = 0; gy < gh; ++gy) {
            const int yi = (py << 2) + gy;
            const int rlo = s_yrl[yi], rhi = s_yrh[yi];
            const float wy0 = s_wy0[yi], wy1 = s_wy1[yi];
            for (int gx = 0; gx < gw; ++gx) {
                const int xi = (px << 2) + gx;
                const int xlo = s_xcl[xi], xhi = s_xch[xi];
                const float wx0 = s_wx0[xi], wx1 = s_wx1[xi];
                const float v00 = sp[rlo + xlo];
                const float v01 = sp[rlo + xhi];
                const float v10 = sp[rhi + xlo];
                const float v11 = sp[rhi + xhi];
                acc += wy0 * (wx0 * v00 + wx1 * v01)
                     + wy1 * (wx0 * v10 + wx1 * v11);
            }
        }
        out[out_base + e] = acc / count;
    }
}

extern "C" void kernel_launch(void* const* d_in, const int* in_sizes, int n_in,
                              void* d_out, int out_size, void* d_ws, size_t ws_size,
                              hipStream_t stream) {
    const float* feat = (const float*)d_in[0];
    const float* rois = (const float*)d_in[1];
    float* out = (float*)d_out;

    const int B = 4, C = 256, H = 200, W = 272;
    const int N = in_sizes[1] / 5;   // 512

    dim3 grid(N, C / CPB);           // 512 x 32
    roi_align_kernel<<<grid, 256, 0, stream>>>(feat, rois, out, B, C, H, W, N);
}

// Round 3
// 333.975 us; speedup vs baseline: 1.8452x; 1.2153x over previous
//
#include <hip/hip_runtime.h>

#define MAXG 4
#define CPB 8                         // channels per block
#define ROWS_MAX 30                   // max region rows (roi<=28 -> span<=30)
#define LDS_STRIDE 37                 // odd row stride: kills pow2 bank aliasing
#define CH_STRIDE (ROWS_MAX * LDS_STRIDE)   // 1110 floats per channel

// Block = (roi, 8-channel chunk), 512 threads.
// Phase 1: build packed geometry tables (int4 per (pixel,grid-slot)) + stage the
//          ROI's feature region into LDS with aligned float4 loads, no int division.
// Phase 2: each thread computes one (channel,pixel) output; taps are 4 LDS reads.
__global__ __launch_bounds__(512, 8) void roi_align_kernel(
    const float* __restrict__ feat,
    const float* __restrict__ rois,
    float* __restrict__ out,
    int C, int H, int W)
{
    const int n    = blockIdx.x;
    const int cblk = blockIdx.y;
    const int t    = threadIdx.x;

    __shared__ float s_feat[CPB * CH_STRIDE];   // 35.5 KB
    __shared__ int4  s_ypack[28];               // {rlo*37, rhi*37, bits(wy0), bits(wy1)}
    __shared__ int4  s_xpack[28];               // {xlo-x0a, xhi-x0a, bits(wx0), bits(wx1)}

    const float* roi = rois + (size_t)n * 5;
    const int   b  = (int)roi[0];
    const float x1 = roi[1], y1 = roi[2], x2 = roi[3], y2 = roi[4];
    const float roi_w = fmaxf(x2 - x1, 1.0f);
    const float roi_h = fmaxf(y2 - y1, 1.0f);
    const float bin_h = roi_h / 7.0f;
    const float bin_w = roi_w / 7.0f;
    int gh = (int)ceilf(roi_h / 7.0f); gh = min(max(gh, 1), MAXG);
    int gw = (int)ceilf(roi_w / 7.0f); gw = min(max(gw, 1), MAXG);
    const float inv_count = 1.0f / (float)(gh * gw);

    // --- region bounds; sample positions are monotone in (pixel, grid-slot)
    auto lo_of = [](float pos, int size) {
        float p = fmaxf(pos, 0.0f);
        return min((int)floorf(p), size - 1);
    };
    const int y0 = lo_of(y1 + 0.5f * bin_h / (float)gh, H);
    const int yE = min(lo_of(y1 + 6.0f * bin_h + ((float)(gh - 1) + 0.5f) * bin_h / (float)gh, H) + 1, H - 1);
    const int x0 = lo_of(x1 + 0.5f * bin_w / (float)gw, W);
    const int xE = min(lo_of(x1 + 6.0f * bin_w + ((float)(gw - 1) + 0.5f) * bin_w / (float)gw, W) + 1, W - 1);
    const int rh    = min(yE - y0 + 1, ROWS_MAX);
    const int x0a   = x0 & ~3;                       // 16B-align region start
    const int spanA = min(xE - x0a + 1, 33);         // cols needed from x0a
    const int CM    = W - 4 - x0a;                   // max aligned quad start in-row (mult of 4)

    // --- packed geometry tables (threads 0..55)
    if (t < 28) {
        const int py = t >> 2, g = t & 3;
        float pos  = y1 + (float)py * bin_h + ((float)g + 0.5f) * bin_h / (float)gh;
        bool valid = (pos >= -1.0f) && (pos <= (float)H);
        float p = fmaxf(pos, 0.0f);
        int lo  = min((int)floorf(p), H - 1);
        int hi  = min(lo + 1, H - 1);
        if (lo >= H - 1) p = (float)(H - 1);
        float frac = p - (float)lo;
        float m = valid ? 1.0f : 0.0f;
        s_ypack[t] = make_int4((lo - y0) * LDS_STRIDE, (hi - y0) * LDS_STRIDE,
                               __float_as_int((1.0f - frac) * m),
                               __float_as_int(frac * m));
    } else if (t < 56) {
        const int u = t - 28;
        const int px = u >> 2, g = u & 3;
        float pos  = x1 + (float)px * bin_w + ((float)g + 0.5f) * bin_w / (float)gw;
        bool valid = (pos >= -1.0f) && (pos <= (float)W);
        float p = fmaxf(pos, 0.0f);
        int lo  = min((int)floorf(p), W - 1);
        int hi  = min(lo + 1, W - 1);
        if (lo >= W - 1) p = (float)(W - 1);
        float frac = p - (float)lo;
        float m = valid ? 1.0f : 0.0f;
        s_xpack[u] = make_int4(lo - x0a, hi - x0a,
                               __float_as_int((1.0f - frac) * m),
                               __float_as_int(frac * m));
    }

    // --- stage region: slots = 8ch x 32rows x 8quads = 2048, shifts only
    const size_t HW = (size_t)H * W;
    const float* fbase = feat + ((size_t)b * C + cblk * CPB) * HW + (size_t)y0 * W + x0a;
    #pragma unroll
    for (int k = 0; k < 4; ++k) {
        const int s  = t + k * 512;
        const int ch = s >> 8;
        const int r  = (s >> 3) & 31;
        const int q  = s & 7;
        if (r < rh) {
            float* sp = s_feat + ch * CH_STRIDE + r * LDS_STRIDE;
            const float* gp = fbase + (size_t)ch * HW + (size_t)r * W;
            const int q4 = q << 2;
            if (q4 < spanA) {
                const int col = min(q4, CM);         // aligned, in-row; dup writes benign
                const float4 v = *(const float4*)(gp + col);
                sp[col + 0] = v.x; sp[col + 1] = v.y; sp[col + 2] = v.z; sp[col + 3] = v.w;
            }
            if (q == 7 && spanA == 33) {             // 9th quad tail (col 32)
                const int col = min(32, CM);         // CM >= spanA-4 = 29 -> covers col 32
                const float4 v = *(const float4*)(gp + col);
                sp[col + 0] = v.x; sp[col + 1] = v.y; sp[col + 2] = v.z; sp[col + 3] = v.w;
            }
        }
    }
    __syncthreads();

    // --- compute: one (channel,pixel) per thread, taps from LDS
    if (t < CPB * 49) {
        const int cl  = t / 49;                      // const divisor -> magic mul
        const int pix = t - cl * 49;
        const int py  = pix / 7;
        const int px  = pix - py * 7;
        const float* sp = s_feat + cl * CH_STRIDE;

        int4 xp[4];
        #pragma unroll
        for (int g = 0; g < 4; ++g) xp[g] = s_xpack[(px << 2) + g];

        float acc = 0.0f;
        #pragma unroll
        for (int gy = 0; gy < MAXG; ++gy) {
            if (gy < gh) {
                const int4 yp = s_ypack[(py << 2) + gy];
                const float wy0 = __int_as_float(yp.z);
                const float wy1 = __int_as_float(yp.w);
                #pragma unroll
                for (int gx = 0; gx < MAXG; ++gx) {
                    if (gx < gw) {
                        const float wx0 = __int_as_float(xp[gx].z);
                        const float wx1 = __int_as_float(xp[gx].w);
                        const float v00 = sp[yp.x + xp[gx].x];
                        const float v01 = sp[yp.x + xp[gx].y];
                        const float v10 = sp[yp.y + xp[gx].x];
                        const float v11 = sp[yp.y + xp[gx].y];
                        acc += wy0 * (wx0 * v00 + wx1 * v01)
                             + wy1 * (wx0 * v10 + wx1 * v11);
                    }
                }
            }
        }
        out[((size_t)n * C + cblk * CPB) * 49 + t] = acc * inv_count;
    }
}

extern "C" void kernel_launch(void* const* d_in, const int* in_sizes, int n_in,
                              void* d_out, int out_size, void* d_ws, size_t ws_size,
                              hipStream_t stream) {
    const float* feat = (const float*)d_in[0];
    const float* rois = (const float*)d_in[1];
    float* out = (float*)d_out;

    const int C = 256, H = 200, W = 272;
    const int N = in_sizes[1] / 5;   // 512

    dim3 grid(N, C / CPB);           // 512 x 32
    roi_align_kernel<<<grid, 512, 0, stream>>>(feat, rois, out, C, H, W);
}